// Round 4
// baseline (433.062 us; speedup 1.0000x reference)
//
#include <hip/hip_runtime.h>
#include <hip/hip_fp16.h>
#include <stdint.h>

typedef __attribute__((ext_vector_type(8))) short short8;
typedef __attribute__((ext_vector_type(8))) unsigned short ushort8;
typedef __attribute__((ext_vector_type(4))) float f32x4;

static __device__ __forceinline__ unsigned short f2bf(float f) {
    union { float f; uint32_t u; } v; v.f = f;
    uint32_t u = v.u;
    u += 0x7fffu + ((u >> 16) & 1u);   // RNE
    return (unsigned short)(u >> 16);
}

// pack 2 fp32 -> bf16x2 (round-half-up): low half = a, high half = b
static __device__ __forceinline__ uint32_t pk_bf16(float a, float b) {
    union { float f; uint32_t u; } ua, ub;
    ua.f = a; ub.f = b;
    return ((ua.u + 0x8000u) >> 16) | ((ub.u + 0x8000u) & 0xffff0000u);
}

#define BSW(n, g) ((g) ^ ((n) & 7))   // XOR granule swizzle (granule = 8 bf16 = 16 B)

// ---------------- W transpose+convert: Wt[n][k] bf16 from W[k][n] fp32 ----------------
__global__ __launch_bounds__(256)
void wt_kernel(const float* __restrict__ W, unsigned short* __restrict__ Wt)
{
    __shared__ float s[32][33];
    const int tx = threadIdx.x;          // 0..31
    const int ty = threadIdx.y;          // 0..7
    const int kBase = blockIdx.x * 32;
    const int nBase = blockIdx.y * 32;
    #pragma unroll
    for (int j = 0; j < 4; ++j)
        s[ty + 8 * j][tx] = W[(size_t)(kBase + ty + 8 * j) * 512 + nBase + tx];
    __syncthreads();
    #pragma unroll
    for (int j = 0; j < 4; ++j)
        Wt[(size_t)(nBase + ty + 8 * j) * 512 + kBase + tx] = f2bf(s[tx][ty + 8 * j]);
}

// ---------------- fused GEMM + IndRNN scan, barrier-free K-loop ----------------
// Grid 512 = 64 b x 8 rb (sharers of b are 64 apart -> same XCD -> L2 reuse of X).
// LDS: Bs[64][512] bf16 swizzled (64 KB, loaded once) + xpL[128][64] fp16 (16 KB) = 80 KB.
__global__ __launch_bounds__(256, 2)
void fused_kernel(const float* __restrict__ X, const unsigned short* __restrict__ Wt,
                  const float* __restrict__ bias, const float* __restrict__ u,
                  float* __restrict__ out)
{
    extern __shared__ unsigned char smem[];
    unsigned short* Bs = (unsigned short*)smem;          // [64][512] bf16, swizzled
    __half*         xpL = (__half*)(smem + 65536);       // [128][64]

    const int tid = threadIdx.x;
    const int bx  = blockIdx.x;
    const int b   = bx & 63;
    const int rb  = bx >> 6;

    const int lane  = tid & 63;
    const int wave  = tid >> 6;
    const int m16   = lane & 15;
    const int quad  = lane >> 4;
    const int waveM = wave & 1;    // 2 waves over t (64 rows each)
    const int waveN = wave >> 1;   // 2 waves over r (32 each)

    // ---- load B tile once (rows rb*64..+64 of Wt), XOR-swizzled ----
    {
        const int w = wave, p = lane;         // position granule = lane
        #pragma unroll
        for (int it = 0; it < 16; ++it) {
            const int n = it * 4 + w;         // row 0..63
            const int g = BSW(n, p);          // source granule
            ushort8 v = *(const ushort8*)(Wt + (size_t)(rb * 64 + n) * 512 + g * 8);
            *(ushort8*)(Bs + n * 512 + p * 8) = v;
        }
    }
    __syncthreads();

    const float ur = u[rb * 64 + lane];
    const float br = bias[rb * 64 + lane];
    float h = 1.0f;

    const float* xB = X + (size_t)b * 1024 * 512;
    f32x4 acc[4][2];

    for (int tt = 0; tt < 8; ++tt) {
        #pragma unroll
        for (int mi = 0; mi < 4; ++mi)
            #pragma unroll
            for (int ni = 0; ni < 2; ++ni)
                acc[mi][ni] = (f32x4){0.f, 0.f, 0.f, 0.f};

        // ---- K-loop: NO barriers. A direct global->reg->bf16, B frags from LDS ----
        #pragma unroll 2
        for (int kk = 0; kk < 16; ++kk) {
            const int k0 = kk * 32 + quad * 8;
            short8 af[4];
            #pragma unroll
            for (int mi = 0; mi < 4; ++mi) {
                const int m = tt * 128 + waveM * 64 + mi * 16 + m16;
                const float* s = xB + (size_t)m * 512 + k0;
                float4 v0 = *(const float4*)(s);
                float4 v1 = *(const float4*)(s + 4);
                union { uint32_t u[4]; short8 s8; } cv;
                cv.u[0] = pk_bf16(v0.x, v0.y);
                cv.u[1] = pk_bf16(v0.z, v0.w);
                cv.u[2] = pk_bf16(v1.x, v1.y);
                cv.u[3] = pk_bf16(v1.z, v1.w);
                af[mi] = cv.s8;
            }
            short8 bf[2];
            #pragma unroll
            for (int ni = 0; ni < 2; ++ni) {
                const int n = waveN * 32 + ni * 16 + m16;
                const int p = BSW(n, kk * 4 + quad);
                bf[ni] = *(const short8*)(Bs + n * 512 + p * 8);
            }
            #pragma unroll
            for (int mi = 0; mi < 4; ++mi)
                #pragma unroll
                for (int ni = 0; ni < 2; ++ni)
                    acc[mi][ni] = __builtin_amdgcn_mfma_f32_16x16x32_bf16(
                        af[mi], bf[ni], acc[mi][ni], 0, 0, 0);
        }

        __syncthreads();   // bar1: wave0's scan of previous tile done -> xpL reusable

        // ---- acc -> xpL fp16; C/D layout (m89): col(r)=lane&15, row(t)=quad*4+reg ----
        #pragma unroll
        for (int mi = 0; mi < 4; ++mi) {
            const int t0 = waveM * 64 + mi * 16 + quad * 4;
            #pragma unroll
            for (int ni = 0; ni < 2; ++ni) {
                const int r = waveN * 32 + ni * 16 + m16;
                #pragma unroll
                for (int rr = 0; rr < 4; ++rr)
                    xpL[(t0 + rr) * 64 + r] = __float2half(acc[mi][ni][rr]);
            }
        }
        __syncthreads();   // bar2: xpL complete

        // ---- wave0 scans this tile while waves 1-3 run the next K-loop ----
        if (wave == 0) {
            float* o = out + ((size_t)b * 1024 + (size_t)tt * 128) * 512 + rb * 64 + lane;
            for (int t0 = 0; t0 < 128; t0 += 16) {
                float v[16];
                #pragma unroll
                for (int j = 0; j < 16; ++j)
                    v[j] = __half2float(xpL[(t0 + j) * 64 + lane]) + br;
                #pragma unroll
                for (int j = 0; j < 16; ++j) {
                    h = fmaxf(fmaf(ur, h, v[j]), 0.0f);
                    o[(size_t)(t0 + j) * 512] = h;
                }
            }
        }
    }
}

extern "C" void kernel_launch(void* const* d_in, const int* in_sizes, int n_in,
                              void* d_out, int out_size, void* d_ws, size_t ws_size,
                              hipStream_t stream) {
    const float* x = (const float*)d_in[0];   // [64,1024,512]
    const float* W = (const float*)d_in[1];   // [512,512]
    const float* u = (const float*)d_in[2];   // [512]
    const float* b = (const float*)d_in[3];   // [512]
    float* out = (float*)d_out;               // [64,1024,512] fp32

    unsigned short* Wt = (unsigned short*)d_ws;   // 512 KB bf16

    dim3 tgrid(16, 16), tblk(32, 8);
    wt_kernel<<<tgrid, tblk, 0, stream>>>(W, Wt);

    const int lds_bytes = 65536 + 16384;          // 80 KB -> 2 blocks/CU
    hipFuncSetAttribute((const void*)fused_kernel,
                        hipFuncAttributeMaxDynamicSharedMemorySize, lds_bytes);
    fused_kernel<<<512, 256, lds_bytes, stream>>>(x, Wt, b, u, out);
}